// Round 2
// baseline (83.831 us; speedup 1.0000x reference)
//
#include <hip/hip_runtime.h>
#include <math.h>

// Hausdorff distance between binary masks on a 96x96 grid, batch 8, mean.
// Single fused kernel:
//   - per-(sample,dir) row set-masks built with wave64 ballots (96 bits/row)
//   - g[r][j] = (nearest set column in row r to j)^2 via ctz/clz on the
//     128-bit row mask (exact, fully parallel)
//   - per-cell min over rows of g[r][j] + (i-r)^2, max over src cells
//   - blocks publish partials with agent-scope release atomics; block 0
//     polls (poison 0xAA.. has bit31 set; real partials >= 0 have bit31
//     clear) and writes mean(max(distA,distB)) to out.

#define HH 96
#define WW 96
#define HW 9216
#define GSTR 97               // +1 pad: conflict-free phase-2 column reads
#define NSLICE 16
#define NBLK (8 * 2 * NSLICE) // 256 blocks = 256 CUs
#define CPS (HW / NSLICE)     // 576 cells per slice
#define BLK 256
#define SENT 1000
#define SENT2 (SENT * SENT)   // 1e6 >> max real d^2 = 18050

__device__ __forceinline__ int imin(int a, int b) { return a < b ? a : b; }

__device__ __forceinline__ int ctz128(__uint128_t x) {
    unsigned long long lo = (unsigned long long)x;
    unsigned long long hi = (unsigned long long)(x >> 64);
    return lo ? __builtin_ctzll(lo) : 64 + __builtin_ctzll(hi);
}
__device__ __forceinline__ int clz128(__uint128_t x) {
    unsigned long long lo = (unsigned long long)x;
    unsigned long long hi = (unsigned long long)(x >> 64);
    return hi ? __builtin_clzll(hi) : 64 + __builtin_clzll(lo);
}

__global__ __launch_bounds__(BLK) void haus_all(
    const float* __restrict__ predict, const float* __restrict__ target,
    unsigned int* __restrict__ ws, float* __restrict__ out)
{
    __shared__ unsigned long long flat[146]; // 144 mask words + pad
    __shared__ int g[HH * GSTR];
    __shared__ float redbuf[BLK / 64];
    __shared__ float hs[8];

    const int bid   = blockIdx.x;
    const int n     = bid >> 5;        // sample
    const int dir   = (bid >> 4) & 1;  // 0: src=A\B tgt=B ; 1: src=B\A tgt=A
    const int slice = bid & 15;
    const int tid   = threadIdx.x;
    const int wave  = tid >> 6, lane = tid & 63;

    const float* pbase = predict + n * HW;
    const float* tbase = target  + n * HW;
    const float* tg    = (dir == 0) ? tbase : pbase;

    // ---- build flat row-major bitmask of the target set (wave64 ballots) ----
    if (tid < 2) flat[144 + tid] = 0ULL;
    for (int i = 0; i < HW / BLK; ++i) {          // 36 iterations
        int p = i * BLK + wave * 64 + lane;
        unsigned long long b = __ballot(tg[p] > 0.5f);
        if (lane == 0) flat[i * 4 + wave] = b;
    }
    __syncthreads();

    // ---- g[r][j]: squared distance to nearest set column in row r ----
    for (int cell = tid; cell < HW; cell += BLK) {
        int r = cell / WW, j = cell - r * WW;
        int bb = r * 96;                           // row's flat bit offset
        int w0 = bb >> 6;                          // off is 0 or 32 only
        unsigned long long lo, hi;
        if (bb & 63) {
            lo = (flat[w0] >> 32) | (flat[w0 + 1] << 32);
            hi = flat[w0 + 1] >> 32;               // 32 bits
        } else {
            lo = flat[w0];
            hi = flat[w0 + 1] & 0xFFFFFFFFULL;
        }
        int d;
        if ((lo | hi) == 0ULL) {
            d = SENT;                              // empty row
        } else {
            __uint128_t m = ((__uint128_t)hi << 64) | lo;
            __uint128_t right = m >> j;            // bits at col >= j
            __uint128_t left  = m << (127 - j);    // bit j -> position 127
            int rd = right ? ctz128(right) : SENT;
            int ld = left  ? clz128(left)  : SENT;
            d = imin(rd, ld);
        }
        g[r * GSTR + j] = d * d;
    }
    __syncthreads();

    // ---- phase 2: per-cell min over rows, max over src cells ----
    float local = 0.0f;
    const int c0 = slice * CPS;
    for (int cc = c0 + tid; cc < c0 + CPS; cc += BLK) {
        int i = cc / WW, j = cc - i * WW;
        bool a = pbase[cc] > 0.5f;
        bool b = tbase[cc] > 0.5f;
        bool src = (dir == 0) ? (a && !b) : (b && !a);

        int mmin = 0x7FFFFFFF;
        #pragma unroll 16
        for (int r = 0; r < HH; ++r) {
            int di = i - r;
            mmin = imin(mmin, g[r * GSTR + j] + di * di);
        }
        if (src) {
            float dmin = (mmin < SENT2) ? sqrtf((float)mmin) * (1.0f / 96.0f)
                                        : 1e9f;   // empty target set -> BIG
            local = fmaxf(local, dmin);
        }
    }

    // ---- block max-reduce, publish partial ----
    for (int off = 32; off; off >>= 1)
        local = fmaxf(local, __shfl_xor(local, off, 64));
    if (lane == 0) redbuf[wave] = local;
    __syncthreads();
    if (tid == 0) {
        float mx = fmaxf(fmaxf(redbuf[0], redbuf[1]),
                         fmaxf(redbuf[2], redbuf[3]));
        __hip_atomic_store(&ws[bid], __float_as_uint(mx),
                           __ATOMIC_RELEASE, __HIP_MEMORY_SCOPE_AGENT);
    }

    // ---- block 0: poll all partials, combine, write scalar ----
    if (bid == 0) {
        if (tid < 8) {
            float mx = 0.0f;
            for (int k = 0; k < 2 * NSLICE; ++k) {   // 32 partials per sample
                unsigned int u;
                do {
                    u = __hip_atomic_load(&ws[tid * (2 * NSLICE) + k],
                                          __ATOMIC_ACQUIRE,
                                          __HIP_MEMORY_SCOPE_AGENT);
                } while (u & 0x80000000u);           // 0xAAAAAAAA poison: bit31 set
                mx = fmaxf(mx, __uint_as_float(u));
            }
            hs[tid] = mx;
        }
        __syncthreads();
        if (tid == 0) {
            float s = 0.0f;
            for (int k = 0; k < 8; ++k) s += hs[k];
            out[0] = s * 0.125f;
        }
    }
}

extern "C" void kernel_launch(void* const* d_in, const int* in_sizes, int n_in,
                              void* d_out, int out_size, void* d_ws, size_t ws_size,
                              hipStream_t stream) {
    const float* predict = (const float*)d_in[0];  // [8,1,96,96] f32
    const float* target  = (const float*)d_in[1];  // [8,1,96,96] f32
    float* out = (float*)d_out;                    // scalar f32
    unsigned int* ws = (unsigned int*)d_ws;        // 256 partial slots

    haus_all<<<dim3(NBLK), dim3(BLK), 0, stream>>>(predict, target, ws, out);
}

// Round 3
// 78.136 us; speedup vs baseline: 1.0729x; 1.0729x over previous
//
#include <hip/hip_runtime.h>
#include <math.h>

// Hausdorff distance between binary masks on a 96x96 grid, batch 8, mean.
// Single fused kernel, parallel completion poll:
//   - per-(sample,dir) row set-masks built with wave64 ballots (96 bits/row)
//   - g[r][j] = (nearest set column in row r to j)^2 via ctz/clz on the
//     128-bit row mask (exact, fully parallel)
//   - per-cell min over rows of g[r][j] + (i-r)^2, max over src cells
//   - blocks publish partials with agent-scope release atomics; block 0's
//     256 threads each poll ONE slot in parallel (poison 0xAA.. has bit31
//     set; real partials have bit31 clear), then LDS-reduce and write
//     mean(max(distA,distB)).

#define HH 96
#define WW 96
#define HW 9216
#define GSTR 97               // +1 pad: conflict-free phase-2 column reads
#define NSLICE 16
#define NBLK (8 * 2 * NSLICE) // 256 blocks = 256 CUs
#define CPS (HW / NSLICE)     // 576 cells per slice
#define BLK 256
#define SENT 1000
#define SENT2 (SENT * SENT)   // 1e6 >> max real d^2 = 18050

__device__ __forceinline__ int imin(int a, int b) { return a < b ? a : b; }

__device__ __forceinline__ int ctz128(__uint128_t x) {
    unsigned long long lo = (unsigned long long)x;
    unsigned long long hi = (unsigned long long)(x >> 64);
    return lo ? __builtin_ctzll(lo) : 64 + __builtin_ctzll(hi);
}
__device__ __forceinline__ int clz128(__uint128_t x) {
    unsigned long long lo = (unsigned long long)x;
    unsigned long long hi = (unsigned long long)(x >> 64);
    return hi ? __builtin_clzll(hi) : 64 + __builtin_clzll(lo);
}

__global__ __launch_bounds__(BLK) void haus_all(
    const float* __restrict__ predict, const float* __restrict__ target,
    unsigned int* __restrict__ ws, float* __restrict__ out)
{
    __shared__ unsigned long long flat[144]; // 9216 mask bits
    __shared__ int g[HH * GSTR];
    __shared__ float redbuf[BLK / 64];
    __shared__ float part[NBLK];             // block 0's poll buffer
    __shared__ float hs[8];

    const int bid   = blockIdx.x;
    const int n     = bid >> 5;        // sample
    const int dir   = (bid >> 4) & 1;  // 0: src=A\B tgt=B ; 1: src=B\A tgt=A
    const int slice = bid & 15;
    const int tid   = threadIdx.x;
    const int wave  = tid >> 6, lane = tid & 63;

    const float* pbase = predict + n * HW;
    const float* tbase = target  + n * HW;
    const float* tg    = (dir == 0) ? tbase : pbase;

    // ---- build flat row-major bitmask of the target set (wave64 ballots) ----
    for (int i = 0; i < HW / BLK; ++i) {          // 36 iterations
        int p = i * BLK + wave * 64 + lane;
        unsigned long long b = __ballot(tg[p] > 0.5f);
        if (lane == 0) flat[i * 4 + wave] = b;
    }
    __syncthreads();

    // ---- g[r][j]: squared distance to nearest set column in row r ----
    for (int cell = tid; cell < HW; cell += BLK) {
        int r = cell / WW, j = cell - r * WW;
        int bb = r * 96;                           // row's flat bit offset
        int w0 = bb >> 6;                          // bb&63 is 0 or 32 only
        unsigned long long lo, hi;
        if (bb & 63) {
            lo = (flat[w0] >> 32) | (flat[w0 + 1] << 32);
            hi = flat[w0 + 1] >> 32;               // 32 bits
        } else {
            lo = flat[w0];
            hi = flat[w0 + 1] & 0xFFFFFFFFULL;
        }
        int d;
        if ((lo | hi) == 0ULL) {
            d = SENT;                              // empty row
        } else {
            __uint128_t m = ((__uint128_t)hi << 64) | lo;
            __uint128_t right = m >> j;            // bits at col >= j
            __uint128_t left  = m << (127 - j);    // bit j -> position 127
            int rd = right ? ctz128(right) : SENT;
            int ld = left  ? clz128(left)  : SENT;
            d = imin(rd, ld);
        }
        g[r * GSTR + j] = d * d;
    }
    __syncthreads();

    // ---- phase 2: per-cell min over rows, max over src cells ----
    float local = 0.0f;
    const int c0 = slice * CPS;
    for (int cc = c0 + tid; cc < c0 + CPS; cc += BLK) {
        int i = cc / WW, j = cc - i * WW;
        bool a = pbase[cc] > 0.5f;
        bool b = tbase[cc] > 0.5f;
        bool src = (dir == 0) ? (a && !b) : (b && !a);

        int mmin = 0x7FFFFFFF;
        #pragma unroll 16
        for (int r = 0; r < HH; ++r) {
            int di = i - r;
            mmin = imin(mmin, g[r * GSTR + j] + di * di);
        }
        if (src) {
            float dmin = (mmin < SENT2) ? sqrtf((float)mmin) * (1.0f / 96.0f)
                                        : 1e9f;   // empty target set -> BIG
            local = fmaxf(local, dmin);
        }
    }

    // ---- block max-reduce, publish partial ----
    for (int off = 32; off; off >>= 1)
        local = fmaxf(local, __shfl_xor(local, off, 64));
    if (lane == 0) redbuf[wave] = local;
    __syncthreads();
    if (tid == 0) {
        float mx = fmaxf(fmaxf(redbuf[0], redbuf[1]),
                         fmaxf(redbuf[2], redbuf[3]));
        __hip_atomic_store(&ws[bid], __float_as_uint(mx),
                           __ATOMIC_RELEASE, __HIP_MEMORY_SCOPE_AGENT);
    }

    // ---- block 0: each thread polls ONE slot in parallel, then reduce ----
    if (bid == 0) {
        unsigned int u;
        do {
            u = __hip_atomic_load(&ws[tid], __ATOMIC_ACQUIRE,
                                  __HIP_MEMORY_SCOPE_AGENT);
        } while (u & 0x80000000u);                 // 0xAAAAAAAA poison: bit31 set
        part[tid] = __uint_as_float(u);
        __syncthreads();
        if (tid < 8) {                             // 32 partials per sample
            float mx = 0.0f;
            for (int k = 0; k < 2 * NSLICE; ++k)
                mx = fmaxf(mx, part[tid * (2 * NSLICE) + k]);
            hs[tid] = mx;
        }
        __syncthreads();
        if (tid == 0) {
            float s = 0.0f;
            for (int k = 0; k < 8; ++k) s += hs[k];
            out[0] = s * 0.125f;
        }
    }
}

extern "C" void kernel_launch(void* const* d_in, const int* in_sizes, int n_in,
                              void* d_out, int out_size, void* d_ws, size_t ws_size,
                              hipStream_t stream) {
    const float* predict = (const float*)d_in[0];  // [8,1,96,96] f32
    const float* target  = (const float*)d_in[1];  // [8,1,96,96] f32
    float* out = (float*)d_out;                    // scalar f32
    unsigned int* ws = (unsigned int*)d_ws;        // 256 partial slots

    haus_all<<<dim3(NBLK), dim3(BLK), 0, stream>>>(predict, target, ws, out);
}